// Round 1
// baseline (352.368 us; speedup 1.0000x reference)
//
#include <hip/hip_runtime.h>
#include <math.h>

// Problem constants
constexpr int B_ = 4, C_ = 192, N_ = 160, M_ = 160;
constexpr int H_ = 4, DH_ = 32, HID_ = 128, NMEM_ = 4;
constexpr int NM_ = N_ * M_;            // 25600
constexpr float SQRT_C = 13.856406460551018f;   // sqrt(192)
constexpr float SCALE_ = 0.17677669529663687f;  // 1/sqrt(32)

__device__ __forceinline__ float wred_sum(float v) {
    #pragma unroll
    for (int o = 32; o > 0; o >>= 1) v += __shfl_xor(v, o, 64);
    return v;
}
__device__ __forceinline__ float wred_max(float v) {
    #pragma unroll
    for (int o = 32; o > 0; o >>= 1) v = fmaxf(v, __shfl_xor(v, o, 64));
    return v;
}

// K0: Wf[t][d][hd] = sum_c Wr[d, t*192+c] * Wo[c,hd];  bf[t][d] = sum_c Wr[d,t*192+c]*bo[c]
__global__ void fusew_kernel(const float* __restrict__ Wr, const float* __restrict__ Wo,
                             const float* __restrict__ bo, float* __restrict__ Wf,
                             float* __restrict__ bfb) {
    int bx = blockIdx.x;              // [0,384): t*192+dch? use t = bx/192
    int t = bx / 192, dch = bx % 192;
    int hd = threadIdx.x;             // 128
    const float* wr = Wr + dch * 384 + t * 192;
    float acc = 0.f;
    for (int c = 0; c < 192; c++) acc += wr[c] * Wo[c * 128 + hd];
    Wf[(t * 192 + dch) * 128 + hd] = acc;
    if (hd == 0) {
        float s = 0.f;
        for (int c = 0; c < 192; c++) s += wr[c] * bo[c];
        bfb[t * 192 + dch] = s;
    }
}

// K1a: partial sum-of-squares over c-chunks of 32.  grid 2400 = 6 chunks * 400
__global__ void ssq_part_kernel(const float* __restrict__ x, float* __restrict__ psum) {
    int bx = blockIdx.x;
    int chunk = bx / 400, blk = bx % 400;
    int g = blk * 256 + threadIdx.x;              // [0,102400)
    int b = g / NM_, nm = g - b * NM_;
    const float* xp = x + ((size_t)(b * C_ + chunk * 32)) * NM_ + nm;
    float ssq = 0.f;
    #pragma unroll
    for (int cc = 0; cc < 32; cc++) { float v = xp[(size_t)cc * NM_]; ssq += v * v; }
    psum[chunk * (B_ * NM_) + g] = ssq;
}

// K1b: rn[b,n,m] = sqrt(C)/max(||x[b,:,n,m]||, 1e-12)
__global__ void rnorm_kernel(const float* __restrict__ psum, float* __restrict__ rn) {
    int g = blockIdx.x * 256 + threadIdx.x;
    float s = 0.f;
    #pragma unroll
    for (int ch = 0; ch < 6; ch++) s += psum[ch * (B_ * NM_) + g];
    rn[g] = SQRT_C / fmaxf(sqrtf(s), 1e-12f);
}

// K23: per (b,c) plane: rowft/Srow (reduce over m), colft/Scol (reduce over n). grid 768
__global__ void rowcol_kernel(const float* __restrict__ x, const float* __restrict__ rn,
                              float* __restrict__ rowft, float* __restrict__ colft,
                              float* __restrict__ Srow, float* __restrict__ Scol) {
    __shared__ float cpart[4][2][160];
    int bc = blockIdx.x;                 // b*192 + c
    int b = bc / C_;
    int tid = threadIdx.x, w = tid >> 6, lane = tid & 63;
    const float* xp = x + (size_t)bc * NM_;
    const float* rp = rn + (size_t)b * NM_;
    int m0 = lane, m1 = lane + 64, m2 = lane + 128;
    bool ok2 = (m2 < M_);
    float cr0 = 0, cr1 = 0, cr2 = 0, cn0 = 0, cn1 = 0, cn2 = 0;
    for (int n = w; n < N_; n += 4) {
        const float* xr = xp + n * M_;
        const float* rr = rp + n * M_;
        float a0 = xr[m0], a1 = xr[m1], a2 = ok2 ? xr[m2] : 0.f;
        float r0 = rr[m0], r1 = rr[m1], r2 = ok2 ? rr[m2] : 0.f;
        float b0 = a0 * r0, b1 = a1 * r1, b2 = a2 * r2;
        cr0 += a0; cr1 += a1; cr2 += a2;
        cn0 += b0; cn1 += b1; cn2 += b2;
        float rs = wred_sum(a0 + a1 + a2);
        float rsn = wred_sum(b0 + b1 + b2);
        if (lane == 0) {
            rowft[bc * N_ + n] = rs * (1.0f / 160.0f);
            Srow[bc * N_ + n] = rsn;
        }
    }
    cpart[w][0][m0] = cr0; cpart[w][0][m1] = cr1; if (ok2) cpart[w][0][m2] = cr2;
    cpart[w][1][m0] = cn0; cpart[w][1][m1] = cn1; if (ok2) cpart[w][1][m2] = cn2;
    __syncthreads();
    if (tid < M_) {
        float sr = cpart[0][0][tid] + cpart[1][0][tid] + cpart[2][0][tid] + cpart[3][0][tid];
        float sn = cpart[0][1][tid] + cpart[1][1][tid] + cpart[2][1][tid] + cpart[3][1][tid];
        colft[bc * M_ + tid] = sr * (1.0f / 160.0f);
        Scol[bc * M_ + tid] = sn;
    }
}

// K4a: channel-normalize rowft->qnrow, colft->qncol. 1 wave per (which,b,pos). grid 320
__global__ void ftnorm_kernel(const float* __restrict__ rowft, const float* __restrict__ colft,
                              float* __restrict__ qnrow, float* __restrict__ qncol) {
    int gw = blockIdx.x * 4 + (threadIdx.x >> 6);     // [0,1280)
    int lane = threadIdx.x & 63;
    int which = gw / 640, rem = gw - which * 640;
    int b = rem / 160, pos = rem - b * 160;
    const float* src = which ? colft : rowft;
    float* dst = which ? qncol : qnrow;
    int base = b * C_ * 160 + pos;
    float v0 = src[base + lane * 160];
    float v1 = src[base + (lane + 64) * 160];
    float v2 = src[base + (lane + 128) * 160];
    float ssq = wred_sum(v0 * v0 + v1 * v1 + v2 * v2);
    float sc = SQRT_C / fmaxf(sqrtf(ssq), 1e-12f);
    dst[base + lane * 160] = v0 * sc;
    dst[base + (lane + 64) * 160] = v1 * sc;
    dst[base + (lane + 128) * 160] = v2 * sc;
}

// K4b: Q/K/Vsum projections. grid 480 = (b,t,mat)*20 pos-tiles, block 256
__global__ void proj_kernel(const float* __restrict__ Wq, const float* __restrict__ Wk,
                            const float* __restrict__ Wv, const float* __restrict__ gq,
                            const float* __restrict__ gk, const float* __restrict__ gv,
                            const float* __restrict__ qnrow, const float* __restrict__ qncol,
                            const float* __restrict__ Srow, const float* __restrict__ Scol,
                            float* __restrict__ Qb, float* __restrict__ Kb, float* __restrict__ Vb) {
    __shared__ float in_s[192 * 8];
    int bx = blockIdx.x;
    int pt = bx % 20, rest = bx / 20;
    int mat = rest % 3; int r2 = rest / 3;
    int t = r2 % 2, b = r2 / 2;
    const float *W, *g, *src; float* dst;
    if (mat == 0)      { W = Wq; g = gq; src = (t == 0) ? qnrow : qncol; dst = Qb; }
    else if (mat == 1) { W = Wk; g = gk; src = (t == 0) ? qncol : qnrow; dst = Kb; }
    else               { W = Wv; g = gv; src = (t == 0) ? Scol  : Srow;  dst = Vb; }
    int tid = threadIdx.x;
    for (int idx = tid; idx < 192 * 8; idx += 256) {
        int c = idx >> 3, p = idx & 7;
        in_s[idx] = g[c] * src[(b * C_ + c) * 160 + pt * 8 + p];
    }
    __syncthreads();
    int hd = tid & 127, pc = tid >> 7;
    float a0 = 0, a1 = 0, a2 = 0, a3 = 0;
    const float* Wrow = W + hd * 192;
    for (int c = 0; c < 192; c++) {
        float wv = Wrow[c];
        const float* ir = &in_s[c * 8 + pc * 4];
        a0 += wv * ir[0]; a1 += wv * ir[1]; a2 += wv * ir[2]; a3 += wv * ir[3];
    }
    int posbase = (b * 2 + t) * 160 + pt * 8 + pc * 4;
    dst[(size_t)(posbase + 0) * 128 + hd] = a0;
    dst[(size_t)(posbase + 1) * 128 + hd] = a1;
    dst[(size_t)(posbase + 2) * 128 + hd] = a2;
    dst[(size_t)(posbase + 3) * 128 + hd] = a3;
}

// K4c: attention per (b,t,h,qtile-of-40). grid 128, block 256
__global__ void attn_kernel(const float* __restrict__ Qb, const float* __restrict__ Kb,
                            const float* __restrict__ Vb, const float* __restrict__ memkv,
                            float* __restrict__ AO) {
    __shared__ float k_s[160 * 33];
    __shared__ float v_s[160 * 33];
    __shared__ float q_s[40 * 33];
    __shared__ float e_s[4 * 160];
    __shared__ float mk[NMEM_ * 32];
    __shared__ float mv[NMEM_ * 32];
    int bx = blockIdx.x;
    int qt = bx & 3, h = (bx >> 2) & 3, t = (bx >> 4) & 1, b = bx >> 5;
    int tid = threadIdx.x, w = tid >> 6, lane = tid & 63;
    int btbase = ((b * 2 + t) * 160) * 128 + h * 32;
    for (int idx = tid; idx < 160 * 32; idx += 256) {
        int kk = idx >> 5, d = idx & 31;
        k_s[kk * 33 + d] = Kb[btbase + kk * 128 + d];
        v_s[kk * 33 + d] = Vb[btbase + kk * 128 + d];
    }
    for (int idx = tid; idx < 40 * 32; idx += 256) {
        int qq = idx >> 5, d = idx & 31;
        q_s[qq * 33 + d] = Qb[btbase + (qt * 40 + qq) * 128 + d];
    }
    if (tid < 128) {
        int j = tid >> 5, d = tid & 31;
        mk[tid] = memkv[(h * 4 + j) * 32 + d];
        mv[tid] = memkv[512 + (h * 4 + j) * 32 + d];
    }
    __syncthreads();
    for (int qq = w; qq < 40; qq += 4) {
        // memory-slot scores (redundant across lanes, LDS broadcast -> cheap)
        float sm[4], smax = -1e30f;
        #pragma unroll
        for (int j = 0; j < 4; j++) {
            float s = 0.f;
            #pragma unroll
            for (int d = 0; d < 32; d++) s += q_s[qq * 33 + d] * mk[j * 32 + d];
            sm[j] = s * SCALE_; smax = fmaxf(smax, sm[j]);
        }
        float sv[3];
        #pragma unroll
        for (int ci = 0; ci < 3; ci++) {
            int k = lane + ci * 64;
            float s = -1e30f;
            if (k < 160) {
                float acc = 0.f;
                #pragma unroll
                for (int d = 0; d < 32; d++) acc += q_s[qq * 33 + d] * k_s[k * 33 + d];
                s = acc * SCALE_;
            }
            sv[ci] = s;
        }
        float mx = fmaxf(fmaxf(sv[0], sv[1]), fmaxf(sv[2], smax));
        mx = wred_max(mx);
        float esum = 0.f;
        #pragma unroll
        for (int ci = 0; ci < 3; ci++) {
            int k = lane + ci * 64;
            if (k < 160) {
                float e = expf(sv[ci] - mx);
                e_s[w * 160 + k] = e;
                esum += e;
            }
        }
        esum = wred_sum(esum);
        float em[4], emsum = 0.f;
        #pragma unroll
        for (int j = 0; j < 4; j++) { em[j] = expf(sm[j] - mx); emsum += em[j]; }
        float Z = emsum + 160.0f * esum;
        // PV: lanes split d x k-half
        int d = lane & 31, half = lane >> 5;
        float acc = 0.f;
        int k0 = half * 80;
        for (int kk = 0; kk < 80; kk++)
            acc += e_s[w * 160 + k0 + kk] * v_s[(k0 + kk) * 33 + d];
        acc += __shfl_down(acc, 32, 64);
        if (half == 0) {
            float accm = 0.f;
            #pragma unroll
            for (int j = 0; j < 4; j++) accm += em[j] * mv[j * 32 + d];
            AO[btbase + (qt * 40 + qq) * 128 + d] = (accm + acc) / Z;
        }
    }
}

// K4d: fused (Wr@Wo) projection: R[b,d,n] / C[b,d,m]. grid 160, block 192
__global__ void oproj_kernel(const float* __restrict__ Wf, const float* __restrict__ bfb,
                             const float* __restrict__ AO, float* __restrict__ Rr,
                             float* __restrict__ Ccv) {
    __shared__ float ao_s[8 * 128];
    int bx = blockIdx.x;
    int pt = bx % 20, rest = bx / 20;
    int t = rest & 1, b = rest >> 1;
    int tid = threadIdx.x;  // 192
    for (int idx = tid; idx < 1024; idx += 192)
        ao_s[idx] = AO[(size_t)((b * 2 + t) * 160 + pt * 8 + (idx >> 7)) * 128 + (idx & 127)];
    __syncthreads();
    int dch = tid;
    float acc[8];
    #pragma unroll
    for (int p = 0; p < 8; p++) acc[p] = 0.f;
    const float* wr = Wf + (t * 192 + dch) * 128;
    for (int hd = 0; hd < 128; hd++) {
        float wv = wr[hd];
        #pragma unroll
        for (int p = 0; p < 8; p++) acc[p] += wv * ao_s[p * 128 + hd];
    }
    float bb = bfb[t * 192 + dch];
    float* dst = t ? Ccv : Rr;
    #pragma unroll
    for (int p = 0; p < 8; p++)
        dst[(b * C_ + dch) * 160 + pt * 8 + p] = acc[p] + bb;
}

// K5: out[b,d,n,m] = R[b,d,n] + C[b,d,m].  grid 768, block 256, float4 stores
__global__ void final_kernel(const float* __restrict__ Rr, const float* __restrict__ Ccv,
                             float* __restrict__ out) {
    __shared__ float Rl[160];
    __shared__ float Cl[160];
    int bd = blockIdx.x;
    int tid = threadIdx.x;
    if (tid < 160) { Rl[tid] = Rr[bd * 160 + tid]; Cl[tid] = Ccv[bd * 160 + tid]; }
    __syncthreads();
    float* base = out + (size_t)bd * NM_;
    for (int idx = tid; idx < 160 * 40; idx += 256) {
        int n = idx / 40, m4 = idx - n * 40;
        float r = Rl[n];
        float4 v;
        v.x = r + Cl[m4 * 4 + 0];
        v.y = r + Cl[m4 * 4 + 1];
        v.z = r + Cl[m4 * 4 + 2];
        v.w = r + Cl[m4 * 4 + 3];
        *reinterpret_cast<float4*>(base + n * 160 + m4 * 4) = v;
    }
}

extern "C" void kernel_launch(void* const* d_in, const int* in_sizes, int n_in,
                              void* d_out, int out_size, void* d_ws, size_t ws_size,
                              hipStream_t stream) {
    const float* x    = (const float*)d_in[0];
    const float* gq   = (const float*)d_in[1];
    const float* gk   = (const float*)d_in[2];
    const float* gv   = (const float*)d_in[3];
    const float* Wq   = (const float*)d_in[4];
    const float* Wk   = (const float*)d_in[5];
    const float* Wv   = (const float*)d_in[6];
    const float* mkv  = (const float*)d_in[7];
    const float* Wo   = (const float*)d_in[8];
    const float* bo   = (const float*)d_in[9];
    const float* Wr   = (const float*)d_in[10];
    float* out = (float*)d_out;

    float* ws = (float*)d_ws;
    // ws layout (floats); total ~1.79M floats (~7.2 MB)
    float* rn    = ws;                  // 102400
    float* rowft = rn    + 102400;      // 122880
    float* colft = rowft + 122880;
    float* Srow  = colft + 122880;
    float* Scol  = Srow  + 122880;
    float* qnrow = Scol  + 122880;
    float* qncol = qnrow + 122880;
    float* Qb    = qncol + 122880;      // 163840
    float* Kb    = Qb    + 163840;
    float* Vb    = Kb    + 163840;
    float* AO    = Vb    + 163840;      // 163840
    float* Rr    = AO    + 163840;      // 122880
    float* Ccv   = Rr    + 122880;
    float* Wf    = Ccv   + 122880;      // 49152
    float* bfb   = Wf    + 49152;       // 384
    float* psum  = Qb;                  // 614400 floats, aliases Qb..AO (dead after K1b)

    fusew_kernel<<<384, 128, 0, stream>>>(Wr, Wo, bo, Wf, bfb);
    ssq_part_kernel<<<2400, 256, 0, stream>>>(x, psum);
    rnorm_kernel<<<400, 256, 0, stream>>>(psum, rn);
    rowcol_kernel<<<768, 256, 0, stream>>>(x, rn, rowft, colft, Srow, Scol);
    ftnorm_kernel<<<320, 256, 0, stream>>>(rowft, colft, qnrow, qncol);
    proj_kernel<<<480, 256, 0, stream>>>(Wq, Wk, Wv, gq, gk, gv,
                                         qnrow, qncol, Srow, Scol, Qb, Kb, Vb);
    attn_kernel<<<128, 256, 0, stream>>>(Qb, Kb, Vb, mkv, AO);
    oproj_kernel<<<160, 192, 0, stream>>>(Wf, bfb, AO, Rr, Ccv);
    final_kernel<<<768, 256, 0, stream>>>(Rr, Ccv, out);
}

// Round 2
// 246.511 us; speedup vs baseline: 1.4294x; 1.4294x over previous
//
#include <hip/hip_runtime.h>
#include <math.h>

// Problem constants
constexpr int B_ = 4, C_ = 192, N_ = 160, M_ = 160;
constexpr int NM_ = N_ * M_;            // 25600
constexpr float SQRT_C = 13.856406460551018f;   // sqrt(192)
constexpr float SCALE_ = 0.17677669529663687f;  // 1/sqrt(32)

__device__ __forceinline__ float wred_sum(float v) {
    #pragma unroll
    for (int o = 32; o > 0; o >>= 1) v += __shfl_xor(v, o, 64);
    return v;
}
__device__ __forceinline__ float wred_max(float v) {
    #pragma unroll
    for (int o = 32; o > 0; o >>= 1) v = fmaxf(v, __shfl_xor(v, o, 64));
    return v;
}

// K0: WfT[hd][t*192+d] = sum_c Wr[d, t*192+c] * Wo[c,hd];  bf[t][d] = sum_c Wr[d,t*192+c]*bo[c]
__global__ void fusew_kernel(const float* __restrict__ Wr, const float* __restrict__ Wo,
                             const float* __restrict__ bo, float* __restrict__ WfT,
                             float* __restrict__ bfb) {
    int bx = blockIdx.x;              // t*192+dch
    int t = bx / 192, dch = bx % 192;
    int hd = threadIdx.x;             // 128
    const float* wr = Wr + dch * 384 + t * 192;
    float acc = 0.f;
    for (int c = 0; c < 192; c++) acc += wr[c] * Wo[c * 128 + hd];
    WfT[hd * 384 + t * 192 + dch] = acc;   // transposed for coalesced oproj reads
    if (hd == 0) {
        float s = 0.f;
        for (int c = 0; c < 192; c++) s += wr[c] * bo[c];
        bfb[t * 192 + dch] = s;
    }
}

// K1a: partial sum-of-squares over c-chunks of 32.  grid 2400 = 6 chunks * 400
__global__ void ssq_part_kernel(const float* __restrict__ x, float* __restrict__ psum) {
    int bx = blockIdx.x;
    int chunk = bx / 400, blk = bx % 400;
    int g = blk * 256 + threadIdx.x;              // [0,102400)
    int b = g / NM_, nm = g - b * NM_;
    const float* xp = x + ((size_t)(b * C_ + chunk * 32)) * NM_ + nm;
    float ssq = 0.f;
    #pragma unroll
    for (int cc = 0; cc < 32; cc++) { float v = xp[(size_t)cc * NM_]; ssq += v * v; }
    psum[chunk * (B_ * NM_) + g] = ssq;
}

// K1b: rn[b,n,m] = sqrt(C)/max(||x[b,:,n,m]||, 1e-12)
__global__ void rnorm_kernel(const float* __restrict__ psum, float* __restrict__ rn) {
    int g = blockIdx.x * 256 + threadIdx.x;
    float s = 0.f;
    #pragma unroll
    for (int ch = 0; ch < 6; ch++) s += psum[ch * (B_ * NM_) + g];
    rn[g] = SQRT_C / fmaxf(sqrtf(s), 1e-12f);
}

// K23: per (b,c) plane: rowft/Srow (reduce over m), colft/Scol (reduce over n). grid 768
__global__ void rowcol_kernel(const float* __restrict__ x, const float* __restrict__ rn,
                              float* __restrict__ rowft, float* __restrict__ colft,
                              float* __restrict__ Srow, float* __restrict__ Scol) {
    __shared__ float cpart[4][2][160];
    int bc = blockIdx.x;                 // b*192 + c
    int b = bc / C_;
    int tid = threadIdx.x, w = tid >> 6, lane = tid & 63;
    const float* xp = x + (size_t)bc * NM_;
    const float* rp = rn + (size_t)b * NM_;
    int m0 = lane, m1 = lane + 64, m2 = lane + 128;
    bool ok2 = (m2 < M_);
    float cr0 = 0, cr1 = 0, cr2 = 0, cn0 = 0, cn1 = 0, cn2 = 0;
    for (int n = w; n < N_; n += 4) {
        const float* xr = xp + n * M_;
        const float* rr = rp + n * M_;
        float a0 = xr[m0], a1 = xr[m1], a2 = ok2 ? xr[m2] : 0.f;
        float r0 = rr[m0], r1 = rr[m1], r2 = ok2 ? rr[m2] : 0.f;
        float b0 = a0 * r0, b1 = a1 * r1, b2 = a2 * r2;
        cr0 += a0; cr1 += a1; cr2 += a2;
        cn0 += b0; cn1 += b1; cn2 += b2;
        float rs = wred_sum(a0 + a1 + a2);
        float rsn = wred_sum(b0 + b1 + b2);
        if (lane == 0) {
            rowft[bc * N_ + n] = rs * (1.0f / 160.0f);
            Srow[bc * N_ + n] = rsn;
        }
    }
    cpart[w][0][m0] = cr0; cpart[w][0][m1] = cr1; if (ok2) cpart[w][0][m2] = cr2;
    cpart[w][1][m0] = cn0; cpart[w][1][m1] = cn1; if (ok2) cpart[w][1][m2] = cn2;
    __syncthreads();
    if (tid < M_) {
        float sr = cpart[0][0][tid] + cpart[1][0][tid] + cpart[2][0][tid] + cpart[3][0][tid];
        float sn = cpart[0][1][tid] + cpart[1][1][tid] + cpart[2][1][tid] + cpart[3][1][tid];
        colft[bc * M_ + tid] = sr * (1.0f / 160.0f);
        Scol[bc * M_ + tid] = sn;
    }
}

// K4a: channel-normalize rowft->qnrow, colft->qncol. 1 wave per (which,b,pos). grid 320
__global__ void ftnorm_kernel(const float* __restrict__ rowft, const float* __restrict__ colft,
                              float* __restrict__ qnrow, float* __restrict__ qncol) {
    int gw = blockIdx.x * 4 + (threadIdx.x >> 6);     // [0,1280)
    int lane = threadIdx.x & 63;
    int which = gw / 640, rem = gw - which * 640;
    int b = rem / 160, pos = rem - b * 160;
    const float* src = which ? colft : rowft;
    float* dst = which ? qncol : qnrow;
    int base = b * C_ * 160 + pos;
    float v0 = src[base + lane * 160];
    float v1 = src[base + (lane + 64) * 160];
    float v2 = src[base + (lane + 128) * 160];
    float ssq = wred_sum(v0 * v0 + v1 * v1 + v2 * v2);
    float sc = SQRT_C / fmaxf(sqrtf(ssq), 1e-12f);
    dst[base + lane * 160] = v0 * sc;
    dst[base + (lane + 64) * 160] = v1 * sc;
    dst[base + (lane + 128) * 160] = v2 * sc;
}

// transpose Wq/Wk/Wv -> WT[mat][c][hd]. grid 288
__global__ void trans_kernel(const float* __restrict__ Wq, const float* __restrict__ Wk,
                             const float* __restrict__ Wv, float* __restrict__ WT) {
    int g = blockIdx.x * 256 + threadIdx.x;     // < 73728
    int mat = g / 24576, r2 = g % 24576;
    int c = r2 >> 7, hd = r2 & 127;
    const float* W = (mat == 0) ? Wq : ((mat == 1) ? Wk : Wv);
    WT[g] = W[hd * 192 + c];
}

// K4b: Q/K/Vsum projections. grid 480 = (b,t,mat)*20 pos-tiles, block 256
__global__ void proj_kernel(const float* __restrict__ WT, const float* __restrict__ gq,
                            const float* __restrict__ gk, const float* __restrict__ gv,
                            const float* __restrict__ qnrow, const float* __restrict__ qncol,
                            const float* __restrict__ Srow, const float* __restrict__ Scol,
                            float* __restrict__ Qb, float* __restrict__ Kb, float* __restrict__ Vb) {
    __shared__ float in_s[192 * 8];
    int bx = blockIdx.x;
    int pt = bx % 20, rest = bx / 20;
    int mat = rest % 3; int r2 = rest / 3;
    int t = r2 % 2, b = r2 / 2;
    const float *g, *src; float* dst;
    if (mat == 0)      { g = gq; src = (t == 0) ? qnrow : qncol; dst = Qb; }
    else if (mat == 1) { g = gk; src = (t == 0) ? qncol : qnrow; dst = Kb; }
    else               { g = gv; src = (t == 0) ? Scol  : Srow;  dst = Vb; }
    const float* Wt = WT + mat * 24576;
    int tid = threadIdx.x;
    for (int idx = tid; idx < 192 * 8; idx += 256) {
        int c = idx >> 3, p = idx & 7;
        in_s[idx] = g[c] * src[(b * C_ + c) * 160 + pt * 8 + p];
    }
    __syncthreads();
    int hd = tid & 127, pc = tid >> 7;
    float a0 = 0, a1 = 0, a2 = 0, a3 = 0;
    for (int c = 0; c < 192; c++) {
        float wv = Wt[c * 128 + hd];             // lane-coalesced
        const float* ir = &in_s[c * 8 + pc * 4]; // LDS broadcast
        a0 += wv * ir[0]; a1 += wv * ir[1]; a2 += wv * ir[2]; a3 += wv * ir[3];
    }
    int posbase = (b * 2 + t) * 160 + pt * 8 + pc * 4;
    dst[(size_t)(posbase + 0) * 128 + hd] = a0;
    dst[(size_t)(posbase + 1) * 128 + hd] = a1;
    dst[(size_t)(posbase + 2) * 128 + hd] = a2;
    dst[(size_t)(posbase + 3) * 128 + hd] = a3;
}

// K4c: attention. grid 640 = (b,t,h)*20 q-tiles of 8, block 256 (4 waves x 2 queries)
__global__ void attn_kernel(const float* __restrict__ Qb, const float* __restrict__ Kb,
                            const float* __restrict__ Vb, const float* __restrict__ memkv,
                            float* __restrict__ AO) {
    __shared__ float k_s[160 * 33];
    __shared__ float v_s[160 * 33];
    __shared__ float q_s[8 * 33];
    __shared__ float e_s[8 * 160];
    __shared__ float mk[128];
    __shared__ float mv[128];
    int bx = blockIdx.x;
    int qt = bx % 20; int r = bx / 20;
    int h = r & 3; r >>= 2;
    int t = r & 1; int b = r >> 1;
    int tid = threadIdx.x, w = tid >> 6, lane = tid & 63;
    int btbase = ((b * 2 + t) * 160) * 128 + h * 32;
    for (int idx = tid; idx < 160 * 32; idx += 256) {
        int kk = idx >> 5, d = idx & 31;
        k_s[kk * 33 + d] = Kb[btbase + kk * 128 + d];
        v_s[kk * 33 + d] = Vb[btbase + kk * 128 + d];
    }
    { int q = tid >> 5, d = tid & 31;
      q_s[q * 33 + d] = Qb[btbase + (qt * 8 + q) * 128 + d]; }
    if (tid < 128) {
        mk[tid] = memkv[h * 128 + tid];
        mv[tid] = memkv[512 + h * 128 + tid];
    }
    __syncthreads();
    // K tile into registers: lane owns keys lane, lane+64, lane+128(<160)
    float kr0[32], kr1[32], kr2[32];
    #pragma unroll
    for (int d = 0; d < 32; d++) {
        kr0[d] = k_s[lane * 33 + d];
        kr1[d] = k_s[(lane + 64) * 33 + d];
        kr2[d] = (lane < 32) ? k_s[(lane + 128) * 33 + d] : 0.f;
    }
    // memory-slot scores for this wave's 2 queries: lane -> (qi=pj>>2, j=pj&3), d-chunk of 4
    float p;
    {
        int pj = lane >> 3, qi = pj >> 2, j = pj & 3;
        int db = (lane & 7) * 4;
        p = 0.f;
        #pragma unroll
        for (int dd = 0; dd < 4; dd++)
            p += q_s[(w * 2 + qi) * 33 + db + dd] * mk[j * 32 + db + dd];
        p += __shfl_xor(p, 1, 64); p += __shfl_xor(p, 2, 64); p += __shfl_xor(p, 4, 64);
        p *= SCALE_;
    }
    float sm[2][4];
    #pragma unroll
    for (int j = 0; j < 4; j++) {
        sm[0][j] = __shfl(p, j * 8, 64);
        sm[1][j] = __shfl(p, 32 + j * 8, 64);
    }
    int dpv = lane & 31;
    float Zq[2], accm[2];
    #pragma unroll
    for (int qi = 0; qi < 2; qi++) {
        int qrow = (w * 2 + qi) * 33;
        float s0 = 0, s1 = 0, s2 = 0;
        #pragma unroll
        for (int d = 0; d < 32; d++) {
            float qv = q_s[qrow + d];            // LDS broadcast
            s0 += qv * kr0[d]; s1 += qv * kr1[d]; s2 += qv * kr2[d];
        }
        s0 *= SCALE_; s1 *= SCALE_;
        s2 = (lane < 32) ? s2 * SCALE_ : -1e30f;
        float mx = fmaxf(fmaxf(s0, s1), s2);
        mx = fmaxf(mx, fmaxf(fmaxf(sm[qi][0], sm[qi][1]), fmaxf(sm[qi][2], sm[qi][3])));
        mx = wred_max(mx);
        float e0 = __expf(s0 - mx), e1 = __expf(s1 - mx);
        float e2 = (lane < 32) ? __expf(s2 - mx) : 0.f;
        int eb = (w * 2 + qi) * 160;
        e_s[eb + lane] = e0; e_s[eb + 64 + lane] = e1;
        if (lane < 32) e_s[eb + 128 + lane] = e2;
        float esum = wred_sum(e0 + e1 + e2);
        float em0 = __expf(sm[qi][0] - mx), em1 = __expf(sm[qi][1] - mx);
        float em2 = __expf(sm[qi][2] - mx), em3 = __expf(sm[qi][3] - mx);
        Zq[qi] = (em0 + em1 + em2 + em3) + 160.0f * esum;
        accm[qi] = em0 * mv[dpv] + em1 * mv[32 + dpv] + em2 * mv[64 + dpv] + em3 * mv[96 + dpv];
    }
    // PV for both queries jointly: half-wave splits keys
    int half = lane >> 5, k0 = half * 80;
    int eb0 = (w * 2) * 160, eb1 = (w * 2 + 1) * 160;
    float a0 = 0, a1 = 0;
    for (int kk = 0; kk < 80; kk++) {
        float v = v_s[(k0 + kk) * 33 + dpv];
        a0 += e_s[eb0 + k0 + kk] * v;
        a1 += e_s[eb1 + k0 + kk] * v;
    }
    a0 += __shfl_down(a0, 32, 64);
    a1 += __shfl_down(a1, 32, 64);
    if (lane < 32) {
        AO[btbase + (qt * 8 + w * 2 + 0) * 128 + lane] = (accm[0] + a0) / Zq[0];
        AO[btbase + (qt * 8 + w * 2 + 1) * 128 + lane] = (accm[1] + a1) / Zq[1];
    }
}

// K4d: fused (Wr@Wo) projection: R[b,d,n] / C[b,d,m]. grid 160, block 192
__global__ void oproj_kernel(const float* __restrict__ WfT, const float* __restrict__ bfb,
                             const float* __restrict__ AO, float* __restrict__ Rr,
                             float* __restrict__ Ccv) {
    __shared__ float ao_s[8 * 128];
    int bx = blockIdx.x;
    int pt = bx % 20, rest = bx / 20;
    int t = rest & 1, b = rest >> 1;
    int tid = threadIdx.x;  // 192
    for (int idx = tid; idx < 1024; idx += 192)
        ao_s[idx] = AO[(size_t)((b * 2 + t) * 160 + pt * 8 + (idx >> 7)) * 128 + (idx & 127)];
    __syncthreads();
    int dch = tid;
    int tofs = t * 192 + dch;
    float acc[8];
    #pragma unroll
    for (int pp = 0; pp < 8; pp++) acc[pp] = 0.f;
    for (int hd = 0; hd < 128; hd++) {
        float wv = WfT[hd * 384 + tofs];     // lane-coalesced
        #pragma unroll
        for (int pp = 0; pp < 8; pp++) acc[pp] += wv * ao_s[pp * 128 + hd];
    }
    float bb = bfb[tofs];
    float* dst = t ? Ccv : Rr;
    #pragma unroll
    for (int pp = 0; pp < 8; pp++)
        dst[(b * C_ + dch) * 160 + pt * 8 + pp] = acc[pp] + bb;
}

// K5: out[b,d,n,m] = R[b,d,n] + C[b,d,m].  grid 768, block 256, float4 stores
__global__ void final_kernel(const float* __restrict__ Rr, const float* __restrict__ Ccv,
                             float* __restrict__ out) {
    __shared__ float Rl[160];
    __shared__ float Cl[160];
    int bd = blockIdx.x;
    int tid = threadIdx.x;
    if (tid < 160) { Rl[tid] = Rr[bd * 160 + tid]; Cl[tid] = Ccv[bd * 160 + tid]; }
    __syncthreads();
    float* base = out + (size_t)bd * NM_;
    for (int idx = tid; idx < 160 * 40; idx += 256) {
        int n = idx / 40, m4 = idx - n * 40;
        float r = Rl[n];
        float4 v;
        v.x = r + Cl[m4 * 4 + 0];
        v.y = r + Cl[m4 * 4 + 1];
        v.z = r + Cl[m4 * 4 + 2];
        v.w = r + Cl[m4 * 4 + 3];
        *reinterpret_cast<float4*>(base + n * 160 + m4 * 4) = v;
    }
}

extern "C" void kernel_launch(void* const* d_in, const int* in_sizes, int n_in,
                              void* d_out, int out_size, void* d_ws, size_t ws_size,
                              hipStream_t stream) {
    const float* x    = (const float*)d_in[0];
    const float* gq   = (const float*)d_in[1];
    const float* gk   = (const float*)d_in[2];
    const float* gv   = (const float*)d_in[3];
    const float* Wq   = (const float*)d_in[4];
    const float* Wk   = (const float*)d_in[5];
    const float* Wv   = (const float*)d_in[6];
    const float* mkv  = (const float*)d_in[7];
    const float* Wo   = (const float*)d_in[8];
    const float* bo   = (const float*)d_in[9];
    const float* Wr   = (const float*)d_in[10];
    float* out = (float*)d_out;

    float* ws = (float*)d_ws;
    // ws layout (floats); total ~1.79M floats (~7.2 MB)
    float* rn    = ws;                  // 102400
    float* rowft = rn    + 102400;      // 122880
    float* colft = rowft + 122880;
    float* Srow  = colft + 122880;
    float* Scol  = Srow  + 122880;
    float* qnrow = Scol  + 122880;
    float* qncol = qnrow + 122880;
    float* Qb    = qncol + 122880;      // 163840
    float* Kb    = Qb    + 163840;
    float* Vb    = Kb    + 163840;
    float* AO    = Vb    + 163840;      // 163840
    float* Rr    = AO    + 163840;      // 122880
    float* Ccv   = Rr    + 122880;
    float* WfT   = Ccv   + 122880;      // 49152
    float* bfb   = WfT   + 49152;       // 384
    float* psum  = Qb;                  // aliases Qb..AO (dead after rnorm)
    float* WT    = rowft;               // aliases rowft (dead after ftnorm); 73728 < 122880

    fusew_kernel<<<384, 128, 0, stream>>>(Wr, Wo, bo, WfT, bfb);
    ssq_part_kernel<<<2400, 256, 0, stream>>>(x, psum);
    rnorm_kernel<<<400, 256, 0, stream>>>(psum, rn);
    rowcol_kernel<<<768, 256, 0, stream>>>(x, rn, rowft, colft, Srow, Scol);
    ftnorm_kernel<<<320, 256, 0, stream>>>(rowft, colft, qnrow, qncol);
    trans_kernel<<<288, 256, 0, stream>>>(Wq, Wk, Wv, WT);
    proj_kernel<<<480, 256, 0, stream>>>(WT, gq, gk, gv,
                                         qnrow, qncol, Srow, Scol, Qb, Kb, Vb);
    attn_kernel<<<640, 256, 0, stream>>>(Qb, Kb, Vb, mkv, AO);
    oproj_kernel<<<160, 192, 0, stream>>>(WfT, bfb, AO, Rr, Ccv);
    final_kernel<<<768, 256, 0, stream>>>(Rr, Ccv, out);
}

// Round 3
// 226.571 us; speedup vs baseline: 1.5552x; 1.0880x over previous
//
#include <hip/hip_runtime.h>
#include <math.h>

// Problem constants
constexpr int B_ = 4, C_ = 192, N_ = 160, M_ = 160;
constexpr int NM_ = N_ * M_;            // 25600
constexpr float SQRT_C = 13.856406460551018f;   // sqrt(192)
constexpr float SCALE_ = 0.17677669529663687f;  // 1/sqrt(32)

__device__ __forceinline__ float wred_sum(float v) {
    #pragma unroll
    for (int o = 32; o > 0; o >>= 1) v += __shfl_xor(v, o, 64);
    return v;
}
__device__ __forceinline__ float wred_max(float v) {
    #pragma unroll
    for (int o = 32; o > 0; o >>= 1) v = fmaxf(v, __shfl_xor(v, o, 64));
    return v;
}

// PREP: blocks 0..191  -> WfT[hd][t*192+d] = sum_c Wr[d,t*192+c]*Wo[c,hd]  (2 dch per block)
//       blocks 192..479 -> WT[mat][c][hd] = g[c] * W[hd*192+c]   (g folded in!)
__global__ void prep_kernel(const float* __restrict__ Wr, const float* __restrict__ Wo,
                            const float* __restrict__ bo,
                            const float* __restrict__ Wq, const float* __restrict__ Wk,
                            const float* __restrict__ Wv, const float* __restrict__ gq,
                            const float* __restrict__ gk, const float* __restrict__ gv,
                            float* __restrict__ WfT, float* __restrict__ bfb,
                            float* __restrict__ WT) {
    int bx = blockIdx.x, tid = threadIdx.x;
    if (bx < 192) {
        int sub = tid >> 7, hd = tid & 127;
        int pair = bx * 2 + sub;             // t*192+dch in [0,384)
        int t = pair / 192, dch = pair % 192;
        const float* wr = Wr + dch * 384 + t * 192;
        float acc = 0.f;
        for (int c = 0; c < 192; c++) acc += wr[c] * Wo[c * 128 + hd];
        WfT[hd * 384 + pair] = acc;
        if (hd == 0) {
            float s = 0.f;
            for (int c = 0; c < 192; c++) s += wr[c] * bo[c];
            bfb[pair] = s;
        }
    } else {
        int g = (bx - 192) * 256 + tid;      // < 73728
        int mat = g / 24576, r2 = g % 24576;
        int c = r2 >> 7, hd = r2 & 127;
        const float* W = (mat == 0) ? Wq : ((mat == 1) ? Wk : Wv);
        const float* gv_ = (mat == 0) ? gq : ((mat == 1) ? gk : gv);
        WT[g] = gv_[c] * W[hd * 192 + c];
    }
}

// K1a: partial sum-of-squares over c-chunks of 32.  grid 2400 = 6 chunks * 400
__global__ void ssq_part_kernel(const float* __restrict__ x, float* __restrict__ psum) {
    int bx = blockIdx.x;
    int chunk = bx / 400, blk = bx % 400;
    int g = blk * 256 + threadIdx.x;              // [0,102400)
    int b = g / NM_, nm = g - b * NM_;
    const float* xp = x + ((size_t)(b * C_ + chunk * 32)) * NM_ + nm;
    float ssq = 0.f;
    #pragma unroll
    for (int cc = 0; cc < 32; cc++) { float v = xp[(size_t)cc * NM_]; ssq += v * v; }
    psum[chunk * (B_ * NM_) + g] = ssq;
}

// K1b: rn[b,n,m] = sqrt(C)/max(||x[b,:,n,m]||, 1e-12)
__global__ void rnorm_kernel(const float* __restrict__ psum, float* __restrict__ rn) {
    int g = blockIdx.x * 256 + threadIdx.x;
    float s = 0.f;
    #pragma unroll
    for (int ch = 0; ch < 6; ch++) s += psum[ch * (B_ * NM_) + g];
    rn[g] = SQRT_C / fmaxf(sqrtf(s), 1e-12f);
}

// K23: per (b,c) plane: rowft/Srow (reduce over m), colft/Scol (reduce over n).
// grid 768, block 512 (8 waves -> 20 serial iters each)
__global__ void rowcol_kernel(const float* __restrict__ x, const float* __restrict__ rn,
                              float* __restrict__ rowft, float* __restrict__ colft,
                              float* __restrict__ Srow, float* __restrict__ Scol) {
    __shared__ float cpart[8][2][160];
    int bc = blockIdx.x;                 // b*192 + c
    int b = bc / C_;
    int tid = threadIdx.x, w = tid >> 6, lane = tid & 63;
    const float* xp = x + (size_t)bc * NM_;
    const float* rp = rn + (size_t)b * NM_;
    int m0 = lane, m1 = lane + 64, m2 = lane + 128;
    bool ok2 = (m2 < M_);
    float cr0 = 0, cr1 = 0, cr2 = 0, cn0 = 0, cn1 = 0, cn2 = 0;
    for (int n = w; n < N_; n += 8) {
        const float* xr = xp + n * M_;
        const float* rr = rp + n * M_;
        float a0 = xr[m0], a1 = xr[m1], a2 = ok2 ? xr[m2] : 0.f;
        float r0 = rr[m0], r1 = rr[m1], r2 = ok2 ? rr[m2] : 0.f;
        float b0 = a0 * r0, b1 = a1 * r1, b2 = a2 * r2;
        cr0 += a0; cr1 += a1; cr2 += a2;
        cn0 += b0; cn1 += b1; cn2 += b2;
        float rs = wred_sum(a0 + a1 + a2);
        float rsn = wred_sum(b0 + b1 + b2);
        if (lane == 0) {
            rowft[bc * N_ + n] = rs * (1.0f / 160.0f);
            Srow[bc * N_ + n] = rsn;
        }
    }
    cpart[w][0][m0] = cr0; cpart[w][0][m1] = cr1; if (ok2) cpart[w][0][m2] = cr2;
    cpart[w][1][m0] = cn0; cpart[w][1][m1] = cn1; if (ok2) cpart[w][1][m2] = cn2;
    __syncthreads();
    if (tid < M_) {
        float sr = 0.f, sn = 0.f;
        #pragma unroll
        for (int ww = 0; ww < 8; ww++) { sr += cpart[ww][0][tid]; sn += cpart[ww][1][tid]; }
        colft[bc * M_ + tid] = sr * (1.0f / 160.0f);
        Scol[bc * M_ + tid] = sn;
    }
}

// K4b: Q/K/Vsum projections with fused per-position RMS norm (g pre-folded into WT).
// grid 960 = (b,t,mat)*40 pos-tiles of 4, block 256
__global__ void proj_kernel(const float* __restrict__ WT,
                            const float* __restrict__ rowft, const float* __restrict__ colft,
                            const float* __restrict__ Srow, const float* __restrict__ Scol,
                            float* __restrict__ Qb, float* __restrict__ Kb, float* __restrict__ Vb) {
    __shared__ float in_s[192 * 4];
    __shared__ float sc_s[4];
    int bx = blockIdx.x;
    int pt = bx % 40, rest = bx / 40;
    int mat = rest % 3; int r2 = rest / 3;
    int t = r2 % 2, b = r2 / 2;
    const float* src; float* dst;
    if (mat == 0)      { src = (t == 0) ? rowft : colft; dst = Qb; }
    else if (mat == 1) { src = (t == 0) ? colft : rowft; dst = Kb; }
    else               { src = (t == 0) ? Scol  : Srow;  dst = Vb; }
    const float* Wt = WT + mat * 24576;
    int tid = threadIdx.x;
    for (int idx = tid; idx < 192 * 4; idx += 256) {
        int c = idx >> 2, p = idx & 3;
        in_s[idx] = src[(b * C_ + c) * 160 + pt * 4 + p];
    }
    __syncthreads();
    int w = tid >> 6, lane = tid & 63;
    if (mat < 2) {
        // per-position channel RMS: wave w handles position w; 192 = 64*3 exactly
        float v0 = in_s[lane * 4 + w];
        float v1 = in_s[(lane + 64) * 4 + w];
        float v2 = in_s[(lane + 128) * 4 + w];
        float ssq = wred_sum(v0 * v0 + v1 * v1 + v2 * v2);
        if (lane == 0) sc_s[w] = SQRT_C / fmaxf(sqrtf(ssq), 1e-12f);
    } else {
        if (tid < 4) sc_s[tid] = 1.0f;
    }
    __syncthreads();
    int hd = tid & 127, pc = tid >> 7, p0 = pc * 2;
    float a0 = 0.f, a1 = 0.f;
    for (int c = 0; c < 192; c++) {
        float wv = Wt[c * 128 + hd];             // lane-coalesced, L2-resident
        a0 += wv * in_s[c * 4 + p0];             // LDS broadcast
        a1 += wv * in_s[c * 4 + p0 + 1];
    }
    int posbase = (b * 2 + t) * 160 + pt * 4 + p0;
    dst[(size_t)posbase * 128 + hd]       = a0 * sc_s[p0];
    dst[(size_t)(posbase + 1) * 128 + hd] = a1 * sc_s[p0 + 1];
}

// K4c: attention. grid 640 = (b,t,h)*20 q-tiles of 8, block 256 (4 waves x 2 queries)
__global__ void attn_kernel(const float* __restrict__ Qb, const float* __restrict__ Kb,
                            const float* __restrict__ Vb, const float* __restrict__ memkv,
                            float* __restrict__ AO) {
    __shared__ float k_s[160 * 33];
    __shared__ float v_s[160 * 33];
    __shared__ float q_s[8 * 33];
    __shared__ float e_s[8 * 160];
    __shared__ float mk[128];
    __shared__ float mv[128];
    int bx = blockIdx.x;
    int qt = bx % 20; int r = bx / 20;
    int h = r & 3; r >>= 2;
    int t = r & 1; int b = r >> 1;
    int tid = threadIdx.x, w = tid >> 6, lane = tid & 63;
    int btbase = ((b * 2 + t) * 160) * 128 + h * 32;
    for (int idx = tid; idx < 160 * 32; idx += 256) {
        int kk = idx >> 5, d = idx & 31;
        k_s[kk * 33 + d] = Kb[btbase + kk * 128 + d];
        v_s[kk * 33 + d] = Vb[btbase + kk * 128 + d];
    }
    { int q = tid >> 5, d = tid & 31;
      q_s[q * 33 + d] = Qb[btbase + (qt * 8 + q) * 128 + d]; }
    if (tid < 128) {
        mk[tid] = memkv[h * 128 + tid];
        mv[tid] = memkv[512 + h * 128 + tid];
    }
    __syncthreads();
    float kr0[32], kr1[32], kr2[32];
    #pragma unroll
    for (int d = 0; d < 32; d++) {
        kr0[d] = k_s[lane * 33 + d];
        kr1[d] = k_s[(lane + 64) * 33 + d];
        kr2[d] = (lane < 32) ? k_s[(lane + 128) * 33 + d] : 0.f;
    }
    float p;
    {
        int pj = lane >> 3, qi = pj >> 2, j = pj & 3;
        int db = (lane & 7) * 4;
        p = 0.f;
        #pragma unroll
        for (int dd = 0; dd < 4; dd++)
            p += q_s[(w * 2 + qi) * 33 + db + dd] * mk[j * 32 + db + dd];
        p += __shfl_xor(p, 1, 64); p += __shfl_xor(p, 2, 64); p += __shfl_xor(p, 4, 64);
        p *= SCALE_;
    }
    float sm[2][4];
    #pragma unroll
    for (int j = 0; j < 4; j++) {
        sm[0][j] = __shfl(p, j * 8, 64);
        sm[1][j] = __shfl(p, 32 + j * 8, 64);
    }
    int dpv = lane & 31;
    float Zq[2], accm[2];
    #pragma unroll
    for (int qi = 0; qi < 2; qi++) {
        int qrow = (w * 2 + qi) * 33;
        float s0 = 0, s1 = 0, s2 = 0;
        #pragma unroll
        for (int d = 0; d < 32; d++) {
            float qv = q_s[qrow + d];
            s0 += qv * kr0[d]; s1 += qv * kr1[d]; s2 += qv * kr2[d];
        }
        s0 *= SCALE_; s1 *= SCALE_;
        s2 = (lane < 32) ? s2 * SCALE_ : -1e30f;
        float mx = fmaxf(fmaxf(s0, s1), s2);
        mx = fmaxf(mx, fmaxf(fmaxf(sm[qi][0], sm[qi][1]), fmaxf(sm[qi][2], sm[qi][3])));
        mx = wred_max(mx);
        float e0 = __expf(s0 - mx), e1 = __expf(s1 - mx);
        float e2 = (lane < 32) ? __expf(s2 - mx) : 0.f;
        int eb = (w * 2 + qi) * 160;
        e_s[eb + lane] = e0; e_s[eb + 64 + lane] = e1;
        if (lane < 32) e_s[eb + 128 + lane] = e2;
        float esum = wred_sum(e0 + e1 + e2);
        float em0 = __expf(sm[qi][0] - mx), em1 = __expf(sm[qi][1] - mx);
        float em2 = __expf(sm[qi][2] - mx), em3 = __expf(sm[qi][3] - mx);
        Zq[qi] = (em0 + em1 + em2 + em3) + 160.0f * esum;
        accm[qi] = em0 * mv[dpv] + em1 * mv[32 + dpv] + em2 * mv[64 + dpv] + em3 * mv[96 + dpv];
    }
    int half = lane >> 5, k0 = half * 80;
    int eb0 = (w * 2) * 160, eb1 = (w * 2 + 1) * 160;
    float a0 = 0, a1 = 0;
    for (int kk = 0; kk < 80; kk++) {
        float v = v_s[(k0 + kk) * 33 + dpv];
        a0 += e_s[eb0 + k0 + kk] * v;
        a1 += e_s[eb1 + k0 + kk] * v;
    }
    a0 += __shfl_down(a0, 32, 64);
    a1 += __shfl_down(a1, 32, 64);
    if (lane < 32) {
        AO[btbase + (qt * 8 + w * 2 + 0) * 128 + lane] = (accm[0] + a0) / Zq[0];
        AO[btbase + (qt * 8 + w * 2 + 1) * 128 + lane] = (accm[1] + a1) / Zq[1];
    }
}

// K4d: fused (Wr@Wo) projection. grid 640 = (b,t)*80 pos-tiles of 2, block 192
__global__ void oproj_kernel(const float* __restrict__ WfT, const float* __restrict__ bfb,
                             const float* __restrict__ AO, float* __restrict__ Rr,
                             float* __restrict__ Ccv) {
    __shared__ float ao_s[2 * 128];
    int bx = blockIdx.x;
    int pt = bx % 80, rest = bx / 80;
    int t = rest & 1, b = rest >> 1;
    int tid = threadIdx.x;  // 192
    for (int idx = tid; idx < 256; idx += 192)
        ao_s[idx] = AO[(size_t)((b * 2 + t) * 160 + pt * 2 + (idx >> 7)) * 128 + (idx & 127)];
    __syncthreads();
    int dch = tid;
    int tofs = t * 192 + dch;
    float a0 = 0.f, a1 = 0.f;
    for (int hd = 0; hd < 128; hd++) {
        float wv = WfT[hd * 384 + tofs];     // lane-coalesced, L2-resident
        a0 += wv * ao_s[hd];
        a1 += wv * ao_s[128 + hd];
    }
    float bb = bfb[tofs];
    float* dst = t ? Ccv : Rr;
    dst[(b * C_ + dch) * 160 + pt * 2 + 0] = a0 + bb;
    dst[(b * C_ + dch) * 160 + pt * 2 + 1] = a1 + bb;
}

// K5: out[b,d,n,m] = R[b,d,n] + C[b,d,m].  grid 768, block 256, float4 stores
__global__ void final_kernel(const float* __restrict__ Rr, const float* __restrict__ Ccv,
                             float* __restrict__ out) {
    __shared__ float Rl[160];
    __shared__ float Cl[160];
    int bd = blockIdx.x;
    int tid = threadIdx.x;
    if (tid < 160) { Rl[tid] = Rr[bd * 160 + tid]; Cl[tid] = Ccv[bd * 160 + tid]; }
    __syncthreads();
    float* base = out + (size_t)bd * NM_;
    for (int idx = tid; idx < 160 * 40; idx += 256) {
        int n = idx / 40, m4 = idx - n * 40;
        float r = Rl[n];
        float4 v;
        v.x = r + Cl[m4 * 4 + 0];
        v.y = r + Cl[m4 * 4 + 1];
        v.z = r + Cl[m4 * 4 + 2];
        v.w = r + Cl[m4 * 4 + 3];
        *reinterpret_cast<float4*>(base + n * 160 + m4 * 4) = v;
    }
}

extern "C" void kernel_launch(void* const* d_in, const int* in_sizes, int n_in,
                              void* d_out, int out_size, void* d_ws, size_t ws_size,
                              hipStream_t stream) {
    const float* x    = (const float*)d_in[0];
    const float* gq   = (const float*)d_in[1];
    const float* gk   = (const float*)d_in[2];
    const float* gv   = (const float*)d_in[3];
    const float* Wq   = (const float*)d_in[4];
    const float* Wk   = (const float*)d_in[5];
    const float* Wv   = (const float*)d_in[6];
    const float* mkv  = (const float*)d_in[7];
    const float* Wo   = (const float*)d_in[8];
    const float* bo   = (const float*)d_in[9];
    const float* Wr   = (const float*)d_in[10];
    float* out = (float*)d_out;

    float* ws = (float*)d_ws;
    float* rn    = ws;                  // 102400
    float* rowft = rn    + 102400;      // 122880
    float* colft = rowft + 122880;
    float* Srow  = colft + 122880;
    float* Scol  = Srow  + 122880;
    float* WT    = Scol  + 122880;      // 73728 (g-folded transposed Wq/Wk/Wv)
    float* Qb    = WT    + 73728;       // 163840
    float* Kb    = Qb    + 163840;
    float* Vb    = Kb    + 163840;
    float* AO    = Vb    + 163840;      // 163840
    float* Rr    = AO    + 163840;      // 122880
    float* Ccv   = Rr    + 122880;
    float* WfT   = Ccv   + 122880;      // 49152
    float* bfb   = WfT   + 49152;       // 384
    float* psum  = Qb;                  // 614400 floats, aliases Qb..AO (dead after rnorm)

    prep_kernel<<<480, 256, 0, stream>>>(Wr, Wo, bo, Wq, Wk, Wv, gq, gk, gv, WfT, bfb, WT);
    ssq_part_kernel<<<2400, 256, 0, stream>>>(x, psum);
    rnorm_kernel<<<400, 256, 0, stream>>>(psum, rn);
    rowcol_kernel<<<768, 512, 0, stream>>>(x, rn, rowft, colft, Srow, Scol);
    proj_kernel<<<960, 256, 0, stream>>>(WT, rowft, colft, Srow, Scol, Qb, Kb, Vb);
    attn_kernel<<<640, 256, 0, stream>>>(Qb, Kb, Vb, mkv, AO);
    oproj_kernel<<<640, 192, 0, stream>>>(WfT, bfb, AO, Rr, Ccv);
    final_kernel<<<768, 256, 0, stream>>>(Rr, Ccv, out);
}